// Round 9
// baseline (130.817 us; speedup 1.0000x reference)
//
#include <hip/hip_runtime.h>

#define BB 2048
#define UU 4096
#define TC 64
#define NSCAN 32

typedef __attribute__((address_space(3))) void lds_void;
typedef __attribute__((address_space(1))) const void gbl_void;

__device__ __forceinline__ void gl_lds16(const float* g, float* l) {
    // async global->LDS DMA: dest = uniform base + lane*16, source per-lane
    __builtin_amdgcn_global_load_lds((gbl_void*)g, (lds_void*)l, 16, 0, 0);
}

// stage one 64x64 tile into swizzled LDS: slot = row*16 + (g ^ (row&7)),
// achieved by pre-swizzling the GLOBAL source (gl_lds dest is linear).
__device__ __forceinline__ void stage_tile(const float* __restrict__ src,
                                           float* dstbase, int brow, int c0, int l) {
    #pragma unroll
    for (int it = 0; it < 16; ++it) {
        int row = (it << 2) + (l >> 4);
        int gsw = (l & 15) ^ (row & 7);
        const float* g = src + (size_t)(brow + row) * UU + (size_t)(c0 + (gsw << 2));
        gl_lds16(g, dstbase + it * 256);
    }
}

__device__ __forceinline__ void poll_ge(volatile int* f, int t) {
    while (*f < t) { }
    asm volatile("" ::: "memory");   // keep dependent LDS reads below the poll
}

__global__ __launch_bounds__(256, 1) void fused_kernel(
    const float* __restrict__ dur,
    const float* __restrict__ speech,
    const float* __restrict__ residual_prev,
    const float* __restrict__ cached_prev,
    const int* __restrict__ unit_len,
    const int* __restrict__ sealed_len,
    const int* __restrict__ committed_prev,
    float* __restrict__ out)
{
    float* mat   = out;
    float* proj  = out + (size_t)BB * UU;
    float* resid = out + 2 * (size_t)BB * UU;
    float* cach  = resid + BB;
    float* comm  = cach + (size_t)BB * UU;

    const int tid = (int)threadIdx.x;

    if (blockIdx.x >= NSCAN) {
        // ---------------- elementwise path: one row per block ----------------
        int r = (int)blockIdx.x - NSCAN;
        int L = min(unit_len[r], sealed_len[r]); L = max(0, min(L, UU));
        int P = committed_prev[r];               P = max(0, min(P, UU));
        int gs = P >> 2, ge = (L + 3) >> 2;
        bool own = P < L;
        size_t base = (size_t)r * UU;
        #pragma unroll
        for (int k2 = 0; k2 < 4; ++k2) {
            int g = (k2 << 8) + tid;                 // group index, coalesced
            if (own && g >= gs && g < ge) continue;  // scan path owns these
            int u0 = g << 2;
            float4 pv = make_float4(0.f, 0.f, 0.f, 0.f);
            if (u0 < P) pv = *reinterpret_cast<const float4*>(cached_prev + base + u0);
            float4 p4, m4;
            p4.x = (u0 + 0 < P) ? pv.x : 0.f;
            p4.y = (u0 + 1 < P) ? pv.y : 0.f;
            p4.z = (u0 + 2 < P) ? pv.z : 0.f;
            p4.w = (u0 + 3 < P) ? pv.w : 0.f;
            m4.x = (u0 + 0 < L) ? p4.x : 0.f;
            m4.y = (u0 + 1 < L) ? p4.y : 0.f;
            m4.z = (u0 + 2 < L) ? p4.z : 0.f;
            m4.w = (u0 + 3 < L) ? p4.w : 0.f;
            *reinterpret_cast<float4*>(mat  + base + u0) = m4;
            *reinterpret_cast<float4*>(proj + base + u0) = p4;
            *reinterpret_cast<float4*>(cach + base + u0) = m4;
        }
        return;
    }

    // -------- scan path: 4 waves, async SPSC pipeline (no barriers) --------
    __shared__ __align__(16) float lin[3][2][64 * TC];   // 96 KB staging ring
    __shared__ __align__(16) float lout[2][64 * TC];     // 32 KB result ring
    __shared__ __align__(16) float lcb[64][4];
    __shared__ int lP[64], lL[64];
    __shared__ int uni2[2];
    __shared__ volatile int flg[4];   // 0: dur staged, 1: speech staged,
                                      // 2: chain done, 3: lout consumed

    const int w = tid >> 6;
    const int l = tid & 63;
    const int brow = (int)blockIdx.x << 6;

    float creg = 0.f;
    int Pl = 0, Lr_ = 0;
    unsigned kspanU = 0;

    if (w == 0) {
        int b = brow + l;
        int Lr = min(unit_len[b], sealed_len[b]); Lr = max(0, min(Lr, UU));
        int Pr = committed_prev[b];               Pr = max(0, min(Pr, UU));
        creg = residual_prev[b];
        lP[l] = Pr; lL[l] = Lr;
        Pl = Pr; Lr_ = Lr;
        bool own = Pr < Lr;
        kspanU = own ? (unsigned)(Lr - Pr) : 0u;
        float4 cbv = make_float4(0.f, 0.f, 0.f, 0.f);
        if (own && (Pr & 3))
            cbv = *reinterpret_cast<const float4*>(cached_prev + (size_t)b * UU + (size_t)(Pr & ~3));
        *reinterpret_cast<float4*>(&lcb[l][0]) = cbv;
        int a = own ? (Pr >> 6) : 0x7fffffff;
        int h = own ? ((Lr + 63) >> 6) : 0;
        #pragma unroll
        for (int d2 = 1; d2 < 64; d2 <<= 1) {
            a = min(a, __shfl_xor(a, d2));
            h = max(h, __shfl_xor(h, d2));
        }
        if (l == 0) {
            uni2[0] = a; uni2[1] = h;
            flg[0] = a - 1; flg[1] = a - 1; flg[2] = a - 1; flg[3] = a - 1;
        }
    }
    __syncthreads();
    const int alo = uni2[0], ahi = uni2[1];

    if (w == 0) {
        // ---------------- chain wave ----------------
        __builtin_amdgcn_s_setprio(1);
        for (int t = alo; t < ahi; ++t) {
            poll_ge(&flg[0], t);       // dur tile staged
            poll_ge(&flg[1], t);       // speech tile staged
            poll_ge(&flg[3], t - 2);   // lout[t&1] free
            const int s3 = t % 3;
            const float* Ld = &lin[s3][0][0];
            const float* Ls = &lin[s3][1][0];
            float* LO = &lout[t & 1][0];
            const int c0 = t << 6;
            const int kP = Pl - c0;

            // whole-tile register hoist: 32 ds_read_b128 issued back-to-back.
            float4 DV[16], SV[16];
            #pragma unroll
            for (int g2 = 0; g2 < 16; ++g2) {
                const int slot = (l << 4) + (g2 ^ (l & 7));
                DV[g2] = *reinterpret_cast<const float4*>(Ld + (slot << 2));
                SV[g2] = *reinterpret_cast<const float4*>(Ls + (slot << 2));
            }
            // PIN the hoist: nothing may be scheduled across this point, so the
            // reads above cannot be re-sunk to their uses (r8's failure mode).
            __builtin_amdgcn_sched_barrier(0);

            float c = creg;
            #pragma unroll
            for (int g2 = 0; g2 < 16; ++g2) {
                const int slot = (l << 4) + (g2 ^ (l & 7));
                float dd[4] = {DV[g2].x, DV[g2].y, DV[g2].z, DV[g2].w};
                float sm[4] = {SV[g2].x, SV[g2].y, SV[g2].z, SV[g2].w};
                float fr[4];
                #pragma unroll
                for (int j = 0; j < 4; ++j) {
                    const int k = (g2 << 2) + j;
                    // identity-carry substitution: inactive -> d=1, m=1 makes the
                    // step an exact identity on c (c in [-1,1)); selects are off
                    // the serial dep chain (prep ops are parallel).
                    bool va = (unsigned)(k - kP) < kspanU;
                    float d_ = va ? dd[j] : 1.0f;
                    float mr = va ? sm[j] : 1.0f;
                    float m_ = rintf(mr);                 // (speech>0.5) as float
                    float s_ = d_ + c;                    // dep 1
                    float f_ = fmaxf(floorf(s_), m_);     // dep 2,3
                    c = fmaxf(s_, 0.f) - f_;              // dep 4 (unconditional)
                    fr[j] = f_;
                }
                *reinterpret_cast<float4*>(LO + (slot << 2)) =
                    make_float4(fr[0], fr[1], fr[2], fr[3]);
            }
            creg = c;
            asm volatile("s_waitcnt lgkmcnt(0)" ::: "memory");  // lout visible
            flg[2] = t;
        }
        __builtin_amdgcn_s_setprio(0);
        int b = brow + l;
        resid[b] = creg;
        comm[b]  = (float)Lr_;
    } else if (w == 3) {
        // ---------------- store wave ----------------
        const int cg = l & 15;
        int Pr16[16], Lr16[16];
        #pragma unroll
        for (int it = 0; it < 16; ++it) {
            int row = (it << 2) + (l >> 4);
            Pr16[it] = lP[row];
            Lr16[it] = lL[row];
        }
        for (int t = alo; t < ahi; ++t) {
            poll_ge(&flg[2], t);
            const float* LO = &lout[t & 1][0];
            float4 vv[16];
            #pragma unroll
            for (int it = 0; it < 16; ++it) {
                const int row = (it << 2) + (l >> 4);
                const int slot = (row << 4) + (cg ^ (row & 7));
                vv[it] = *reinterpret_cast<const float4*>(LO + (slot << 2));
            }
            asm volatile("s_waitcnt lgkmcnt(0)" ::: "memory");  // reads retired
            flg[3] = t;                                         // free lout early
            #pragma unroll
            for (int it = 0; it < 16; ++it) {
                const int row = (it << 2) + (l >> 4);
                float4 v = vv[it];
                const int gg = (t << 4) + cg;
                const int Pr = Pr16[it], Lr = Lr16[it];
                const int u0 = gg << 2;
                bool instore = (Pr < Lr) && (gg >= (Pr >> 2)) && (gg < ((Lr + 3) >> 2));
                if (instore) {
                    if (u0 < Pr) {                     // partial P-boundary group
                        float4 cbv = *reinterpret_cast<const float4*>(&lcb[row][0]);
                        v.x = (u0 + 0 >= Pr) ? v.x : cbv.x;
                        v.y = (u0 + 1 >= Pr) ? v.y : cbv.y;
                        v.z = (u0 + 2 >= Pr) ? v.z : cbv.z;
                        v.w = (u0 + 3 >= Pr) ? v.w : cbv.w;
                    }
                    if (u0 + 4 > Lr) {                 // partial L-tail group
                        v.x = (u0 + 0 < Lr) ? v.x : 0.f;
                        v.y = (u0 + 1 < Lr) ? v.y : 0.f;
                        v.z = (u0 + 2 < Lr) ? v.z : 0.f;
                        v.w = (u0 + 3 < Lr) ? v.w : 0.f;
                    }
                    size_t o = (size_t)(brow + row) * UU + (size_t)u0;
                    *reinterpret_cast<float4*>(mat  + o) = v;
                    *reinterpret_cast<float4*>(proj + o) = v;
                    *reinterpret_cast<float4*>(cach + o) = v;
                }
            }
        }
    } else {
        // ---------------- stage waves (w==1: dur, w==2: speech) ----------------
        const float* src = (w == 1) ? dur : speech;
        volatile int* myf = &flg[w - 1];
        const int arr = w - 1;
        for (int q = alo; q < ahi; ++q) {
            poll_ge(&flg[2], q - 3);                 // lin slot q%3 free
            stage_tile(src, &lin[q % 3][arr][0], brow, q << 6, l);
            // in-order vm retirement: <=16 outstanding => tile q-1 landed
            asm volatile("s_waitcnt vmcnt(16)" ::: "memory");
            *myf = q - 1;
        }
        if (alo < ahi) {
            asm volatile("s_waitcnt vmcnt(0)" ::: "memory");
            *myf = ahi - 1;
        }
    }
}

extern "C" void kernel_launch(void* const* d_in, const int* in_sizes, int n_in,
                              void* d_out, int out_size, void* d_ws, size_t ws_size,
                              hipStream_t stream) {
    const float* dur            = (const float*)d_in[0];
    const float* speech         = (const float*)d_in[1];
    const float* residual_prev  = (const float*)d_in[2];
    const float* cached_prev    = (const float*)d_in[3];
    const int*   unit_len       = (const int*)d_in[4];
    const int*   sealed_len     = (const int*)d_in[5];
    const int*   committed_prev = (const int*)d_in[6];

    fused_kernel<<<NSCAN + BB, 256, 0, stream>>>(dur, speech, residual_prev, cached_prev,
                                                 unit_len, sealed_len, committed_prev,
                                                 (float*)d_out);
}

// Round 10
// 121.599 us; speedup vs baseline: 1.0758x; 1.0758x over previous
//
#include <hip/hip_runtime.h>

#define BB 2048
#define UU 4096
#define TC 64
#define ROWS 16
#define NSCAN (BB / ROWS)        // 128 scan blocks, 16 rows each

typedef __attribute__((address_space(3))) void lds_void;
typedef __attribute__((address_space(1))) const void gbl_void;

__device__ __forceinline__ void gl_lds16(const float* g, float* l) {
    // async global->LDS DMA: dest = uniform base + lane*16, source per-lane
    __builtin_amdgcn_global_load_lds((gbl_void*)g, (lds_void*)l, 16, 0, 0);
}

// stage one 16x64 tile into swizzled LDS: f4-slot = row*16 + (g ^ (row&7)),
// achieved by pre-swizzling the GLOBAL source (gl_lds dest is linear).
__device__ __forceinline__ void stage_tile(const float* __restrict__ src,
                                           float* dstbase, int brow, int c0, int l) {
    #pragma unroll
    for (int it = 0; it < 4; ++it) {
        int row = (it << 2) + (l >> 4);
        int gsw = (l & 15) ^ (row & 7);
        const float* g = src + (size_t)(brow + row) * UU + (size_t)(c0 + (gsw << 2));
        gl_lds16(g, dstbase + it * 256);
    }
}

__global__ __launch_bounds__(256, 1) void fused_kernel(
    const float* __restrict__ dur,
    const float* __restrict__ speech,
    const float* __restrict__ residual_prev,
    const float* __restrict__ cached_prev,
    const int* __restrict__ unit_len,
    const int* __restrict__ sealed_len,
    const int* __restrict__ committed_prev,
    float* __restrict__ out)
{
    float* mat   = out;
    float* proj  = out + (size_t)BB * UU;
    float* resid = out + 2 * (size_t)BB * UU;
    float* cach  = resid + BB;
    float* comm  = cach + (size_t)BB * UU;

    const int tid = (int)threadIdx.x;

    if (blockIdx.x >= NSCAN) {
        // ---------------- elementwise path: one row per block ----------------
        int r = (int)blockIdx.x - NSCAN;
        int L = min(unit_len[r], sealed_len[r]); L = max(0, min(L, UU));
        int P = committed_prev[r];               P = max(0, min(P, UU));
        int gs = P >> 2, ge = (L + 3) >> 2;
        bool own = P < L;
        size_t base = (size_t)r * UU;
        #pragma unroll
        for (int k2 = 0; k2 < 4; ++k2) {
            int g = (k2 << 8) + tid;                 // group index, coalesced
            if (own && g >= gs && g < ge) continue;  // scan path owns these
            int u0 = g << 2;
            float4 pv = make_float4(0.f, 0.f, 0.f, 0.f);
            if (u0 < P) pv = *reinterpret_cast<const float4*>(cached_prev + base + u0);
            float4 p4, m4;
            p4.x = (u0 + 0 < P) ? pv.x : 0.f;
            p4.y = (u0 + 1 < P) ? pv.y : 0.f;
            p4.z = (u0 + 2 < P) ? pv.z : 0.f;
            p4.w = (u0 + 3 < P) ? pv.w : 0.f;
            m4.x = (u0 + 0 < L) ? p4.x : 0.f;
            m4.y = (u0 + 1 < L) ? p4.y : 0.f;
            m4.z = (u0 + 2 < L) ? p4.z : 0.f;
            m4.w = (u0 + 3 < L) ? p4.w : 0.f;
            *reinterpret_cast<float4*>(mat  + base + u0) = m4;
            *reinterpret_cast<float4*>(proj + base + u0) = p4;
            *reinterpret_cast<float4*>(cach + base + u0) = m4;
        }
        return;
    }

    // -------- scan path: 4 waves, async SPSC pipeline (no barriers) --------
    __shared__ __align__(16) float lin[3][2][ROWS * TC];  // 24 KB staging ring
    __shared__ __align__(16) float lout[2][ROWS * TC];    // 8 KB result ring
    __shared__ __align__(16) float lcb[ROWS][4];
    __shared__ int lP[ROWS], lL[ROWS];
    __shared__ int uni2[2];
    __shared__ volatile int flg[4];   // 0: dur staged, 1: speech staged,
                                      // 2: chain done, 3: lout consumed

    const int w = tid >> 6;
    const int l = tid & 63;
    const int brow = (int)blockIdx.x * ROWS;

    float creg = 0.f;
    int Pl = 0, Lr_ = 0;
    unsigned kspanU = 0;

    if (w == 0) {
        const bool valid = (l < ROWS);
        int Lr = 0, Pr = 0;
        if (valid) {
            int b = brow + l;
            Lr = min(unit_len[b], sealed_len[b]); Lr = max(0, min(Lr, UU));
            Pr = committed_prev[b];               Pr = max(0, min(Pr, UU));
            creg = residual_prev[b];
            lP[l] = Pr; lL[l] = Lr;
            Pl = Pr; Lr_ = Lr;
            bool own = Pr < Lr;
            kspanU = own ? (unsigned)(Lr - Pr) : 0u;
            float4 cbv = make_float4(0.f, 0.f, 0.f, 0.f);
            if (own && (Pr & 3))
                cbv = *reinterpret_cast<const float4*>(
                    cached_prev + (size_t)b * UU + (size_t)(Pr & ~3));
            *reinterpret_cast<float4*>(&lcb[l][0]) = cbv;
        }
        int a = (valid && Pl < Lr_) ? (Pl >> 6) : 0x7fffffff;
        int h = (valid && Pl < Lr_) ? ((Lr_ + 63) >> 6) : 0;
        #pragma unroll
        for (int d2 = 1; d2 < 64; d2 <<= 1) {
            a = min(a, __shfl_xor(a, d2));
            h = max(h, __shfl_xor(h, d2));
        }
        if (l == 0) {
            uni2[0] = a; uni2[1] = h;
            flg[0] = a - 1; flg[1] = a - 1; flg[2] = a - 1; flg[3] = a - 1;
        }
    }
    __syncthreads();
    const int alo = uni2[0], ahi = uni2[1];

    if (w == 0) {
        // ---------------- chain wave ----------------
        __builtin_amdgcn_s_setprio(1);
        for (int t = alo; t < ahi; ++t) {
            // merged poll: one LDS round trip checks all three conditions
            for (;;) {
                int f0 = flg[0]; int f1 = flg[1]; int f3 = flg[3];
                if (f0 >= t && f1 >= t && f3 >= t - 2) break;
            }
            asm volatile("" ::: "memory");
            const int s3 = t % 3;
            if (l < ROWS) {
                const float* Ld = &lin[s3][0][0];
                const float* Ls = &lin[s3][1][0];
                float* LO = &lout[t & 1][0];
                const int c0 = t << 6;
                const int kP = Pl - c0;
                float c = creg;
                #pragma unroll
                for (int g2 = 0; g2 < 16; ++g2) {
                    const int slot = (l << 4) + (g2 ^ (l & 7));
                    float4 dv = *reinterpret_cast<const float4*>(Ld + (slot << 2));
                    float4 sv = *reinterpret_cast<const float4*>(Ls + (slot << 2));
                    float dd[4] = {dv.x, dv.y, dv.z, dv.w};
                    float sm[4] = {sv.x, sv.y, sv.z, sv.w};
                    float fr[4];
                    #pragma unroll
                    for (int j = 0; j < 4; ++j) {
                        const int k = (g2 << 2) + j;
                        // identity-carry substitution: inactive -> d=1, m=1 makes
                        // the step exact identity on c (c in (-1,1)); selects are
                        // off the serial dep chain.
                        bool va = (unsigned)(k - kP) < kspanU;
                        float d_ = va ? dd[j] : 1.0f;
                        float mr = va ? sm[j] : 1.0f;
                        float m_ = rintf(mr);                 // (speech>0.5)
                        float s_ = d_ + c;                    // dep 1
                        float f_ = fmaxf(floorf(s_), m_);     // dep 2,3
                        c = fmaxf(s_, 0.f) - f_;              // dep 4
                        fr[j] = f_;
                    }
                    *reinterpret_cast<float4*>(LO + (slot << 2)) =
                        make_float4(fr[0], fr[1], fr[2], fr[3]);
                }
                creg = c;
            }
            asm volatile("s_waitcnt lgkmcnt(0)" ::: "memory");  // lout visible
            if (l == 0) flg[2] = t;
        }
        __builtin_amdgcn_s_setprio(0);
        if (l < ROWS) {
            int b = brow + l;
            resid[b] = creg;
            comm[b]  = (float)Lr_;
        }
    } else if (w == 3) {
        // ---------------- store wave ----------------
        const int cg = l & 15;
        int Pr4[4], Lr4[4];
        #pragma unroll
        for (int it = 0; it < 4; ++it) {
            int row = (it << 2) + (l >> 4);
            Pr4[it] = lP[row];
            Lr4[it] = lL[row];
        }
        for (int t = alo; t < ahi; ++t) {
            poll: { while (flg[2] < t) { } }
            asm volatile("" ::: "memory");
            const float* LO = &lout[t & 1][0];
            float4 vv[4];
            #pragma unroll
            for (int it = 0; it < 4; ++it) {
                const int row = (it << 2) + (l >> 4);
                const int slot = (row << 4) + (cg ^ (row & 7));
                vv[it] = *reinterpret_cast<const float4*>(LO + (slot << 2));
            }
            asm volatile("s_waitcnt lgkmcnt(0)" ::: "memory");  // reads retired
            if (l == 0) flg[3] = t;                             // free lout early
            #pragma unroll
            for (int it = 0; it < 4; ++it) {
                const int row = (it << 2) + (l >> 4);
                float4 v = vv[it];
                const int gg = (t << 4) + cg;
                const int Pr = Pr4[it], Lr = Lr4[it];
                const int u0 = gg << 2;
                bool instore = (Pr < Lr) && (gg >= (Pr >> 2)) && (gg < ((Lr + 3) >> 2));
                if (instore) {
                    if (u0 < Pr) {                     // partial P-boundary group
                        float4 cbv = *reinterpret_cast<const float4*>(&lcb[row][0]);
                        v.x = (u0 + 0 >= Pr) ? v.x : cbv.x;
                        v.y = (u0 + 1 >= Pr) ? v.y : cbv.y;
                        v.z = (u0 + 2 >= Pr) ? v.z : cbv.z;
                        v.w = (u0 + 3 >= Pr) ? v.w : cbv.w;
                    }
                    if (u0 + 4 > Lr) {                 // partial L-tail group
                        v.x = (u0 + 0 < Lr) ? v.x : 0.f;
                        v.y = (u0 + 1 < Lr) ? v.y : 0.f;
                        v.z = (u0 + 2 < Lr) ? v.z : 0.f;
                        v.w = (u0 + 3 < Lr) ? v.w : 0.f;
                    }
                    size_t o = (size_t)(brow + row) * UU + (size_t)u0;
                    *reinterpret_cast<float4*>(mat  + o) = v;
                    *reinterpret_cast<float4*>(proj + o) = v;
                    *reinterpret_cast<float4*>(cach + o) = v;
                }
            }
        }
    } else {
        // ---------------- stage waves (w==1: dur, w==2: speech) ----------------
        const float* src = (w == 1) ? dur : speech;
        volatile int* myf = &flg[w - 1];
        const int arr = w - 1;
        for (int q = alo; q < ahi; ++q) {
            while (flg[2] < q - 3) { }               // lin slot q%3 free
            asm volatile("" ::: "memory");
            stage_tile(src, &lin[q % 3][arr][0], brow, q << 6, l);
            // in-order vm retirement: <=4 outstanding => tile q-1 landed
            asm volatile("s_waitcnt vmcnt(4)" ::: "memory");
            if (l == 0) *myf = q - 1;
        }
        if (alo < ahi) {
            asm volatile("s_waitcnt vmcnt(0)" ::: "memory");
            if (l == 0) *myf = ahi - 1;
        }
    }
}

extern "C" void kernel_launch(void* const* d_in, const int* in_sizes, int n_in,
                              void* d_out, int out_size, void* d_ws, size_t ws_size,
                              hipStream_t stream) {
    const float* dur            = (const float*)d_in[0];
    const float* speech         = (const float*)d_in[1];
    const float* residual_prev  = (const float*)d_in[2];
    const float* cached_prev    = (const float*)d_in[3];
    const int*   unit_len       = (const int*)d_in[4];
    const int*   sealed_len     = (const int*)d_in[5];
    const int*   committed_prev = (const int*)d_in[6];

    fused_kernel<<<NSCAN + BB, 256, 0, stream>>>(dur, speech, residual_prev, cached_prev,
                                                 unit_len, sealed_len, committed_prev,
                                                 (float*)d_out);
}